// Round 1
// baseline (133.052 us; speedup 1.0000x reference)
//
#include <hip/hip_runtime.h>

// FusedSOSCascade: 8-section biquad cascade (DF2T), C=128, T=65536, fp32.
// R4: occupancy push. R3 ran 1024 waves = exactly 1 wave/SIMD (LDS-capped),
// measured 107.4 us vs ~8.5 us VALU-issue bound => ~92% stalled with zero
// TLP to hide anything (and likely DVFS down-clock at 8% busy).
// waves/SIMD = 128/L_CHK, so: L 128 -> 32, W stays 192.
//   * 4096 blocks x 64 thr = 4096 waves = 4 waves/SIMD (LDS 9.2 KB/block,
//     16 blocks/CU; VGPR capped 128 via __launch_bounds__(64,4)).
//   * per-wave critical path shrinks 0.7x (224 steps vs 320).
//   * issue bound rises to ~24 us (amplification 7x) -- still << 107 us.
// LDS pad: +1 float per 32 (thread stride 33): read bank = (tid+t)%32 ->
// 2-way, free (m136). (The old per-128 pad would be 4-way at L=32.)
// Warm-up W=192: 0.95^192 ~ 5e-5 decay, truncation << 3.5e-2 threshold.

#define T_LEN   65536
#define L_CHK   32                        // output samples per thread
#define W_WARM  192                       // warm-up samples per thread
#define CPB     64                        // chunks per block (= threads)
#define SPAN    (CPB * L_CHK)             // 2048 samples per block
#define LDS_RAW (W_WARM + SPAN)           // 2240 floats
#define LDS_PAD (LDS_RAW + LDS_RAW / 32)  // 2310 floats (~9.24 KB)
#define NSTEP   (W_WARM + L_CHK)          // 224 steps = 28 groups of 8
#define NGRP    (NSTEP / 8)               // 28
#define OUTG    (W_WARM / 8)              // first output group = 24

// One DF2T cascade step: s = section input, updated in place to output.
#define CASCADE_STEP(s)                                        \
  do {                                                         \
    _Pragma("unroll")                                          \
    for (int k = 0; k < 8; ++k) {                              \
      float y  = fmaf(b0c[k], (s), z1s[k]);                    \
      z1s[k]   = fmaf(b1c[k], (s), fmaf(na1c[k], y, z2s[k]));  \
      z2s[k]   = fmaf(b2c[k], (s), na2c[k] * y);               \
      (s) = y;                                                 \
    }                                                          \
  } while (0)

// Load 8 samples of group `grp` (steps t=8*grp..8*grp+7) into buf[8].
// Raw index r0 = tid*32 + 8*grp; padded = r0 + r0/32. A 32-float pad
// boundary never falls inside a group (r0 % 32 in {0,8,16,24}).
#define LOADGRP(buf, grp)                                      \
  do {                                                         \
    const int r0 = (tid << 5) + 8 * (grp);                     \
    const int gb = r0 + (r0 >> 5);                             \
    _Pragma("unroll")                                          \
    for (int j = 0; j < 8; ++j) (buf)[j] = lds[gb + j];        \
  } while (0)

// Run 8 cascade steps from buf; groups >= OUTG store 8 outputs (two float4).
#define STEPGRP(buf, grp)                                      \
  do {                                                         \
    float ys[8];                                               \
    _Pragma("unroll")                                          \
    for (int j = 0; j < 8; ++j) {                              \
      float s = (buf)[j];                                      \
      CASCADE_STEP(s);                                         \
      ys[j] = s;                                               \
    }                                                          \
    if ((grp) >= OUTG) {                                       \
      const int o = 8 * ((grp) - OUTG);                        \
      *(float4*)(op + o)     = make_float4(ys[0], ys[1], ys[2], ys[3]); \
      *(float4*)(op + o + 4) = make_float4(ys[4], ys[5], ys[6], ys[7]); \
    }                                                          \
  } while (0)

__global__ __launch_bounds__(64, 4)
void FusedSOSCascade_20040317403806_kernel(const float* __restrict__ x,
                                           const float* __restrict__ sos,
                                           float* __restrict__ out) {
  __shared__ float lds[LDS_PAD];

  const int tid  = threadIdx.x;          // 0..63
  const int blk  = blockIdx.x;           // 0..4095
  const int ch   = blk >> 5;             // 32 blocks per channel
  const int part = blk & 31;
  const float* xc = x + (size_t)ch * T_LEN;
  const int span0 = part * SPAN;

  // ---- Stage global -> LDS: 560 float4s per block, 9 per thread, all
  // issued before any ds_write waitcnt so 9 HBM requests are in flight.
  {
    float4 v[9];
#pragma unroll
    for (int k = 0; k < 9; ++k) {
      const int m = (tid + (k << 6)) << 2;        // raw float index, %4==0
      const int g = span0 - W_WARM + m;
      float4 t = make_float4(0.f, 0.f, 0.f, 0.f);
      if (m < LDS_RAW && g >= 0) t = *(const float4*)(xc + g);
      v[k] = t;
    }
#pragma unroll
    for (int k = 0; k < 9; ++k) {
      const int m = (tid + (k << 6)) << 2;
      if (m < LDS_RAW) {
        const int id = m + (m >> 5);   // pad every 32 floats; m%4==0 so a
        lds[id]     = v[k].x;          // float4 never straddles a pad
        lds[id + 1] = v[k].y;
        lds[id + 2] = v[k].z;
        lds[id + 3] = v[k].w;
      }
    }
  }
  __syncthreads();

  // ---- Coefficients (a0 == 1.0 by construction; divide anyway).
  float b0c[8], b1c[8], b2c[8], na1c[8], na2c[8];
#pragma unroll
  for (int k = 0; k < 8; ++k) {
    const float a0 = sos[k * 6 + 3];
    b0c[k]  =  sos[k * 6 + 0] / a0;
    b1c[k]  =  sos[k * 6 + 1] / a0;
    b2c[k]  =  sos[k * 6 + 2] / a0;
    na1c[k] = -(sos[k * 6 + 4] / a0);
    na2c[k] = -(sos[k * 6 + 5] / a0);
  }

  // ---- DF2T state at rest.
  float z1s[8], z2s[8];
#pragma unroll
  for (int k = 0; k < 8; ++k) { z1s[k] = z2s[k] = 0.f; }

  float* op = out + (size_t)ch * T_LEN + span0 + tid * L_CHK;

  // ---- 28 groups of 8 steps, software-pipelined: load g+1 before compute g.
  float buf0[8], buf1[8];
  LOADGRP(buf0, 0);
#pragma unroll 1
  for (int gp = 0; gp < 13; ++gp) {
    const int gA = 2 * gp;
    LOADGRP(buf1, gA + 1);
    STEPGRP(buf0, gA);
    LOADGRP(buf0, gA + 2);
    STEPGRP(buf1, gA + 1);
  }
  LOADGRP(buf1, 27);
  STEPGRP(buf0, 26);
  STEPGRP(buf1, 27);
}

extern "C" void kernel_launch(void* const* d_in, const int* in_sizes, int n_in,
                              void* d_out, int out_size, void* d_ws, size_t ws_size,
                              hipStream_t stream) {
  const float* x   = (const float*)d_in[0];   // [128, 65536] fp32
  const float* sos = (const float*)d_in[1];   // [8, 6] fp32
  float* out = (float*)d_out;                 // [128, 65536] fp32
  (void)in_sizes; (void)n_in; (void)out_size; (void)d_ws; (void)ws_size;

  FusedSOSCascade_20040317403806_kernel<<<dim3(4096), dim3(64), 0, stream>>>(
      x, sos, out);
}

// Round 2
// 125.588 us; speedup vs baseline: 1.0594x; 1.0594x over previous
//
#include <hip/hip_runtime.h>

// FusedSOSCascade: 8-section biquad cascade (DF2T), C=128, T=65536, fp32.
// R5: residency push via multi-wave workgroups + W cut.
// R4 evidence: per-wave issue duty ~10% (identical to R3) -> each wave is
// latency-bound; throughput scales linearly with resident waves/SIMD.
// OccupancyPercent=27% showed only ~8.6 waves/CU resident despite 16 planned
// (per-CU workgroup-slot cap with single-wave blocks). Fix: 256-thread
// blocks (4 waves) sharing one LDS stage -> 1024 blocks x 34 KB LDS ->
// 4 blocks/CU x 4 waves = 16 waves/CU (4/SIMD).
// Also W 192->160: 0.95^160 ~ 2.7e-4 decay, truncation ~1e-3 << 3.5e-2
// threshold; instruction count -14% (NSTEP 224->192).
// Work model: 192 steps x 40 VALU x 2cyc x 4096 waves / 1024 SIMD
// = 61,440 cyc/SIMD = 25.6 us ideal @2.4GHz.

#define T_LEN   65536
#define L_CHK   32                        // output samples per thread
#define W_WARM  160                       // warm-up samples per thread
#define TPB     256                       // threads per block (4 waves)
#define SPAN    (TPB * L_CHK)             // 8192 samples per block
#define LDS_RAW (W_WARM + SPAN)           // 8352 floats
#define LDS_PAD (LDS_RAW + LDS_RAW / 32)  // 8613 floats (~34.4 KB)
#define NSTEP   (W_WARM + L_CHK)          // 192 steps = 24 groups of 8
#define NGRP    (NSTEP / 8)               // 24
#define OUTG    (W_WARM / 8)              // first output group = 20

// One DF2T cascade step: s = section input, updated in place to output.
#define CASCADE_STEP(s)                                        \
  do {                                                         \
    _Pragma("unroll")                                          \
    for (int k = 0; k < 8; ++k) {                              \
      float y  = fmaf(b0c[k], (s), z1s[k]);                    \
      z1s[k]   = fmaf(b1c[k], (s), fmaf(na1c[k], y, z2s[k]));  \
      z2s[k]   = fmaf(b2c[k], (s), na2c[k] * y);               \
      (s) = y;                                                 \
    }                                                          \
  } while (0)

// Load 8 samples of group `grp` (steps t=8*grp..8*grp+7) into buf[8].
// Raw index r0 = tid*32 + 8*grp; padded = r0 + r0/32. A 32-float pad
// boundary never falls inside a group (r0 % 32 in {0,8,16,24}).
// Read bank = (33*tid + c) % 32 -> lanes map 2-way per bank: free (m136).
#define LOADGRP(buf, grp)                                      \
  do {                                                         \
    const int r0 = (tid << 5) + 8 * (grp);                     \
    const int gb = r0 + (r0 >> 5);                             \
    _Pragma("unroll")                                          \
    for (int j = 0; j < 8; ++j) (buf)[j] = lds[gb + j];        \
  } while (0)

// Run 8 cascade steps from buf; groups >= OUTG store 8 outputs (two float4).
#define STEPGRP(buf, grp)                                      \
  do {                                                         \
    float ys[8];                                               \
    _Pragma("unroll")                                          \
    for (int j = 0; j < 8; ++j) {                               \
      float s = (buf)[j];                                      \
      CASCADE_STEP(s);                                         \
      ys[j] = s;                                               \
    }                                                          \
    if ((grp) >= OUTG) {                                       \
      const int o = 8 * ((grp) - OUTG);                        \
      *(float4*)(op + o)     = make_float4(ys[0], ys[1], ys[2], ys[3]); \
      *(float4*)(op + o + 4) = make_float4(ys[4], ys[5], ys[6], ys[7]); \
    }                                                          \
  } while (0)

__global__ __launch_bounds__(TPB, 4)
void FusedSOSCascade_20040317403806_kernel(const float* __restrict__ x,
                                           const float* __restrict__ sos,
                                           float* __restrict__ out) {
  __shared__ float lds[LDS_PAD];

  const int tid  = threadIdx.x;          // 0..255
  const int blk  = blockIdx.x;           // 0..1023
  const int ch   = blk >> 3;             // 8 blocks per channel
  const int part = blk & 7;
  const float* xc = x + (size_t)ch * T_LEN;
  const int span0 = part * SPAN;

  // ---- Stage global -> LDS: 2088 float4s per block, up to 9 per thread,
  // all issued before any ds_write waitcnt so 9 HBM requests are in flight.
  {
    float4 v[9];
#pragma unroll
    for (int k = 0; k < 9; ++k) {
      const int m = (tid + (k << 8)) << 2;        // raw float index, %4==0
      const int g = span0 - W_WARM + m;
      float4 t = make_float4(0.f, 0.f, 0.f, 0.f);
      if (m < LDS_RAW && g >= 0) t = *(const float4*)(xc + g);
      v[k] = t;
    }
#pragma unroll
    for (int k = 0; k < 9; ++k) {
      const int m = (tid + (k << 8)) << 2;
      if (m < LDS_RAW) {
        const int id = m + (m >> 5);   // pad every 32 floats; m%4==0 and
        lds[id]     = v[k].x;          // m%32<=28 so a float4 never
        lds[id + 1] = v[k].y;          // straddles a pad
        lds[id + 2] = v[k].z;
        lds[id + 3] = v[k].w;
      }
    }
  }
  __syncthreads();

  // ---- Coefficients (a0 == 1.0 by construction; divide anyway).
  float b0c[8], b1c[8], b2c[8], na1c[8], na2c[8];
#pragma unroll
  for (int k = 0; k < 8; ++k) {
    const float a0 = sos[k * 6 + 3];
    b0c[k]  =  sos[k * 6 + 0] / a0;
    b1c[k]  =  sos[k * 6 + 1] / a0;
    b2c[k]  =  sos[k * 6 + 2] / a0;
    na1c[k] = -(sos[k * 6 + 4] / a0);
    na2c[k] = -(sos[k * 6 + 5] / a0);
  }

  // ---- DF2T state at rest.
  float z1s[8], z2s[8];
#pragma unroll
  for (int k = 0; k < 8; ++k) { z1s[k] = z2s[k] = 0.f; }

  float* op = out + (size_t)ch * T_LEN + span0 + tid * L_CHK;

  // ---- 24 groups of 8 steps, software-pipelined: load g+1 before compute g.
  float buf0[8], buf1[8];
  LOADGRP(buf0, 0);
#pragma unroll 1
  for (int gp = 0; gp < (NGRP - 2) / 2; ++gp) {   // 11 iterations
    const int gA = 2 * gp;
    LOADGRP(buf1, gA + 1);
    STEPGRP(buf0, gA);
    LOADGRP(buf0, gA + 2);
    STEPGRP(buf1, gA + 1);
  }
  LOADGRP(buf1, NGRP - 1);
  STEPGRP(buf0, NGRP - 2);
  STEPGRP(buf1, NGRP - 1);
}

extern "C" void kernel_launch(void* const* d_in, const int* in_sizes, int n_in,
                              void* d_out, int out_size, void* d_ws, size_t ws_size,
                              hipStream_t stream) {
  const float* x   = (const float*)d_in[0];   // [128, 65536] fp32
  const float* sos = (const float*)d_in[1];   // [8, 6] fp32
  float* out = (float*)d_out;                 // [128, 65536] fp32
  (void)in_sizes; (void)n_in; (void)out_size; (void)d_ws; (void)ws_size;

  FusedSOSCascade_20040317403806_kernel<<<dim3(1024), dim3(TPB), 0, stream>>>(
      x, sos, out);
}